// Round 8
// baseline (11369.604 us; speedup 1.0000x reference)
//
#include <hip/hip_runtime.h>

#define NB  8
#define NPT 4096
#define NS  1024
#define NK  32
#define DIN 6
#define QPB 32          // queries per mega-block
#define MEGA_THREADS 1024

// mega LDS float offsets
#define OFF_A   0            // 131*128 = 16768
#define OFF_W1  16768        // 64*64   = 4096
#define OFF_W2  20864        // 128*64  = 8192
#define OFF_W0  29056        // 64*9    = 576
#define OFF_H1  29632        // 32*68   = 2176
#define OFF_H2  31808        // 32*68   = 2176
#define OFF_U   33984        // 32*132  = 4224
#define FLT_TOT 38208
#define SMEM_BYTES (FLT_TOT * 4)   // 152832 B <= 160 KiB

// ---------------------------------------------------------------------------
__device__ __forceinline__ float bnrelu(float acc, const float* __restrict__ bb,
                                        const float* __restrict__ gg,
                                        const float* __restrict__ be,
                                        const float* __restrict__ mm,
                                        const float* __restrict__ vv, int oc) {
  float t = (acc + bb[oc]) - mm[oc];
  float val = gg[oc] * t * rsqrtf(vv[oc] + 1e-5f) + be[oc];
  return fmaxf(val, 0.0f);
}

// ---------------------------------------------------------------------------
// Wave64 max via DPP + readlane(63). Identity = -1.0f.
// ---------------------------------------------------------------------------
__device__ __forceinline__ float wave64_max(float x) {
  const int NEG1 = 0xbf800000;
  int v;
  v = __builtin_amdgcn_update_dpp(NEG1, __float_as_int(x), 0x111, 0xf, 0xf, false);
  x = fmaxf(x, __int_as_float(v));
  v = __builtin_amdgcn_update_dpp(NEG1, __float_as_int(x), 0x112, 0xf, 0xf, false);
  x = fmaxf(x, __int_as_float(v));
  v = __builtin_amdgcn_update_dpp(NEG1, __float_as_int(x), 0x114, 0xf, 0xf, false);
  x = fmaxf(x, __int_as_float(v));
  v = __builtin_amdgcn_update_dpp(NEG1, __float_as_int(x), 0x118, 0xf, 0xf, false);
  x = fmaxf(x, __int_as_float(v));
  v = __builtin_amdgcn_update_dpp(NEG1, __float_as_int(x), 0x142, 0xa, 0xf, false);
  x = fmaxf(x, __int_as_float(v));
  v = __builtin_amdgcn_update_dpp(NEG1, __float_as_int(x), 0x143, 0xc, 0xf, false);
  x = fmaxf(x, __int_as_float(v));
  return __int_as_float(__builtin_amdgcn_readlane(__float_as_int(x), 63));
}

// ---------------------------------------------------------------------------
// Kernel 1: FPS v6. 1024 threads x 4 points (16 waves = 4/SIMD for latency
// overlap; issue work conserved). Selection semantics identical to verified
// v1-v5: exact __f*_rn distance order, per-thread first-max (ascending j),
// wave ffs(ballot), ascending-wave left-favored tournament (right wins only
// on strict >).
// ---------------------------------------------------------------------------
__global__ __launch_bounds__(1024) void fps_kernel(const float* __restrict__ xyz,
                                                   int* __restrict__ fps_idx,
                                                   float* __restrict__ nxyz,
                                                   float* __restrict__ out0) {
  const int b = blockIdx.x;
  const int t = threadIdx.x;
  const int lane = t & 63, wid = t >> 6;   // wid 0..15
  const float* xb = xyz + (size_t)b * 3 * NPT;

  __shared__ float s_x[NPT], s_y[NPT], s_z[NPT];
  __shared__ __align__(16) float s_red[2][16][2];
  __shared__ float s_ox[NS], s_oy[NS], s_oz[NS];
  __shared__ int s_fi[NS];

  float px[4], py[4], pz[4], dist[4];
  const int base = t * 4;
#pragma unroll
  for (int j = 0; j < 4; ++j) {
    px[j] = xb[base + j];
    py[j] = xb[NPT + base + j];
    pz[j] = xb[2 * NPT + base + j];
    dist[j] = 1e10f;
  }
  for (int i = t; i < NPT; i += 1024) {
    s_x[i] = xb[i];
    s_y[i] = xb[NPT + i];
    s_z[i] = xb[2 * NPT + i];
  }
  __syncthreads();

  int far = 0;
  float cx = xb[0], cy = xb[NPT], cz = xb[2 * NPT];

  for (int s = 0; s < NS; ++s) {
    if (t == 0) {
      s_ox[s] = cx; s_oy[s] = cy; s_oz[s] = cz; s_fi[s] = far;
    }
    float bv = -1.0f;
    int bi = 0;
#pragma unroll
    for (int j = 0; j < 4; ++j) {
      float dx = __fsub_rn(px[j], cx);
      float dy = __fsub_rn(py[j], cy);
      float dz = __fsub_rn(pz[j], cz);
      float d = __fadd_rn(__fadd_rn(__fmul_rn(dx, dx), __fmul_rn(dy, dy)),
                          __fmul_rn(dz, dz));
      float nd = fminf(dist[j], d);
      dist[j] = nd;
      bi = (nd > bv) ? (base + j) : bi;
      bv = fmaxf(bv, nd);
    }
    float mv = wave64_max(bv);
    unsigned long long mmask = __ballot(bv == mv);
    int src = __ffsll(mmask) - 1;
    int wi = __shfl(bi, src);

    const int p = s & 1;
    if (lane == 0) {
      s_red[p][wid][0] = mv;
      s_red[p][wid][1] = __int_as_float(wi);
    }
    __syncthreads();

    // 16-slot left-favored tournament in registers (uniform LDS broadcast)
    float v8[8]; int i8[8];
#pragma unroll
    for (int w = 0; w < 8; ++w) {
      float4 qq = *(const float4*)&s_red[p][w * 2][0];
      bool g = qq.z > qq.x;
      v8[w] = g ? qq.z : qq.x;
      i8[w] = g ? __float_as_int(qq.w) : __float_as_int(qq.y);
    }
#pragma unroll
    for (int off = 1; off < 8; off <<= 1) {
#pragma unroll
      for (int i = 0; i < 8; i += 2 * off) {
        bool g = v8[i + off] > v8[i];
        v8[i] = g ? v8[i + off] : v8[i];
        i8[i] = g ? i8[i + off] : i8[i];
      }
    }
    far = i8[0];
    cx = s_x[far]; cy = s_y[far]; cz = s_z[far];
  }

  __syncthreads();
  for (int i = t; i < NS; i += 1024) {
    float X = s_ox[i], Y = s_oy[i], Z = s_oz[i];
    out0[((size_t)b * 3 + 0) * NS + i] = X;
    out0[((size_t)b * 3 + 1) * NS + i] = Y;
    out0[((size_t)b * 3 + 2) * NS + i] = Z;
    nxyz[((size_t)b * NS + i) * 3 + 0] = X;
    nxyz[((size_t)b * NS + i) * 3 + 1] = Y;
    nxyz[((size_t)b * NS + i) * 3 + 2] = Z;
    fps_idx[b * NS + i] = s_fi[i];
  }
}

// ---------------------------------------------------------------------------
// Kernel 2: center-point MLP + center half of attention scores. (unchanged)
// ---------------------------------------------------------------------------
__global__ __launch_bounds__(64) void center_kernel(
    const float* __restrict__ points, const float* __restrict__ nxyz,
    const int* __restrict__ fps_idx,
    const float* __restrict__ w0, const float* __restrict__ b0,
    const float* __restrict__ g0, const float* __restrict__ be0,
    const float* __restrict__ m0, const float* __restrict__ v0,
    const float* __restrict__ w1, const float* __restrict__ b1,
    const float* __restrict__ g1, const float* __restrict__ be1,
    const float* __restrict__ m1, const float* __restrict__ v1,
    const float* __restrict__ w2, const float* __restrict__ b2,
    const float* __restrict__ g2, const float* __restrict__ be2,
    const float* __restrict__ m2, const float* __restrict__ v2,
    const float* __restrict__ a, float* __restrict__ ceA) {
  const int bs = blockIdx.x;
  const int b = bs >> 10;
  const int t = threadIdx.x;

  __shared__ float ci[9];
  __shared__ float ch1[64];
  __shared__ float ch2[64];
  __shared__ float ch3[128];

  if (t < 9) {
    ci[t] = (t < 3) ? nxyz[(size_t)bs * 3 + t]
                    : points[((size_t)b * DIN + (t - 3)) * NPT + fps_idx[bs]];
  }
  __syncthreads();
  {
    float acc = 0.f;
#pragma unroll
    for (int c = 0; c < 9; ++c) acc = fmaf(ci[c], w0[t * 9 + c], acc);
    ch1[t] = bnrelu(acc, b0, g0, be0, m0, v0, t);
  }
  __syncthreads();
  {
    float acc = 0.f;
#pragma unroll 8
    for (int c = 0; c < 64; ++c) acc = fmaf(ch1[c], w1[t * 64 + c], acc);
    ch2[t] = bnrelu(acc, b1, g1, be1, m1, v1, t);
  }
  __syncthreads();
  for (int oc = t; oc < 128; oc += 64) {
    float acc = 0.f;
#pragma unroll 8
    for (int c = 0; c < 64; ++c) acc = fmaf(ch2[c], w2[oc * 64 + c], acc);
    ch3[oc] = bnrelu(acc, b2, g2, be2, m2, v2, oc);
  }
  __syncthreads();
  for (int oc = t; oc < 128; oc += 64) {
    float acc = 0.f;
#pragma unroll 8
    for (int c = 0; c < 128; ++c) acc = fmaf(ch3[c], a[(3 + c) * 128 + oc], acc);
    ceA[(size_t)bs * 128 + oc] = acc;
  }
}

// ---------------------------------------------------------------------------
// Kernel 3: standalone ball query + gather (unchanged, verified).
// ---------------------------------------------------------------------------
__global__ __launch_bounds__(256) void ballq_kernel(
    const float* __restrict__ xyz, const float* __restrict__ nxyz,
    float4* __restrict__ gq) {
  const int bs = blockIdx.x;
  const int b = bs >> 10;
  const int t = threadIdx.x;
  const int lane = t & 63;
  const int wid = t >> 6;

  __shared__ int s_widx[4][NK];
  __shared__ int s_wc[4];

  const float* xb = xyz + (size_t)b * 3 * NPT;
  const float cx = nxyz[(size_t)bs * 3 + 0];
  const float cy = nxyz[(size_t)bs * 3 + 1];
  const float cz = nxyz[(size_t)bs * 3 + 2];

  {
    const float R2 = (float)(0.15 * 0.15);
    float s2c = __fadd_rn(__fadd_rn(__fmul_rn(cx, cx), __fmul_rn(cy, cy)),
                          __fmul_rn(cz, cz));
    int wcnt = 0;
    for (int g = 0; g < 16; ++g) {
      int n = wid * 1024 + g * 64 + lane;
      float x = xb[n];
      float y = xb[NPT + n];
      float z = xb[2 * NPT + n];
      float pn2 = __fadd_rn(__fadd_rn(__fmul_rn(x, x), __fmul_rn(y, y)),
                            __fmul_rn(z, z));
      float dot = fmaf(cz, z, fmaf(cy, y, __fmul_rn(cx, x)));
      float sqr = __fsub_rn(__fadd_rn(s2c, pn2), __fmul_rn(2.0f, dot));
      bool hit = !(sqr > R2);
      unsigned long long mm = __ballot(hit);
      int pos = wcnt + __popcll(mm & ((1ull << lane) - 1ull));
      if (hit && pos < NK) s_widx[wid][pos] = n;
      wcnt += __popcll(mm);
      if (wcnt >= NK) break;  // wave-uniform
    }
    if (lane == 0) s_wc[wid] = (wcnt < NK) ? wcnt : NK;
  }
  __syncthreads();

  if (t < NK) {
    int c0 = s_wc[0], c1 = s_wc[1], c2 = s_wc[2], c3 = s_wc[3];
    int total = c0 + c1 + c2 + c3;
    int cc[4] = {c0, c1, c2, c3};
    int p = (t < total) ? t : 0;  // pad misses with overall-first hit
    int w = 0;
    while (w < 3 && p >= cc[w]) { p -= cc[w]; ++w; }
    int n = s_widx[w][p];
    float gx = __fsub_rn(xb[n], cx);
    float gy = __fsub_rn(xb[NPT + n], cy);
    float gz = __fsub_rn(xb[2 * NPT + n], cz);
    gq[(size_t)bs * NK + t] = make_float4(gx, gy, gz, __int_as_float(n));
  }
}

// ---------------------------------------------------------------------------
// Kernel 4 (mega v3): 1024 threads (16 waves = 4/SIMD), 32 queries/block,
// 256 blocks. Per-thread work halved vs v2 (C/D: 2 oc, E/F: 4 oc), weights
// LDS-resident, 3 barriers/query, software prefetch of gv/points for q+1.
// Thread map: k = t&31 (neighbor row), g32 = t>>5 (0..31 oc-group).
// ---------------------------------------------------------------------------
__global__ __launch_bounds__(MEGA_THREADS) void mega_kernel(
    const float* __restrict__ points, const float* __restrict__ ceA,
    const float4* __restrict__ gq,
    const float* __restrict__ w0, const float* __restrict__ b0,
    const float* __restrict__ g0, const float* __restrict__ be0,
    const float* __restrict__ m0, const float* __restrict__ v0,
    const float* __restrict__ w1, const float* __restrict__ b1,
    const float* __restrict__ g1, const float* __restrict__ be1,
    const float* __restrict__ m1, const float* __restrict__ v1,
    const float* __restrict__ w2, const float* __restrict__ b2,
    const float* __restrict__ g2, const float* __restrict__ be2,
    const float* __restrict__ m2, const float* __restrict__ v2,
    const float* __restrict__ a, float* __restrict__ out1) {
  extern __shared__ float lds[];
  float* s_a  = lds + OFF_A;
  float* s_w1 = lds + OFF_W1;
  float* s_w2 = lds + OFF_W2;
  float* s_w0 = lds + OFF_W0;
  float* s_h1 = lds + OFF_H1;
  float* s_h2 = lds + OFF_H2;
  float* s_u  = lds + OFF_U;

  const int t = threadIdx.x;
  const int k = t & 31;             // neighbor row
  const int g32 = t >> 5;           // oc group 0..31

  // ---- stage weights into LDS (once per block) ----
  {
    const float4* srcA = (const float4*)a;
    float4* dstA = (float4*)s_a;
    for (int i = t; i < 4192; i += MEGA_THREADS) dstA[i] = srcA[i];
    const float4* src1 = (const float4*)w1;
    float4* dst1 = (float4*)s_w1;
    for (int i = t; i < 1024; i += MEGA_THREADS) dst1[i] = src1[i];
    const float4* src2 = (const float4*)w2;
    float4* dst2 = (float4*)s_w2;
    for (int i = t; i < 2048; i += MEGA_THREADS) dst2[i] = src2[i];
    for (int i = t; i < 576; i += MEGA_THREADS) s_w0[i] = w0[i];
  }
  __syncthreads();

  const int bs0 = blockIdx.x * QPB;

  // prologue: load q=0's neighbor record + point features
  float4 gv = gq[(size_t)bs0 * NK + k];
  float pts[6];
  {
    int n = __float_as_int(gv.w);
    const float* pb = points + (size_t)(bs0 >> 10) * DIN * NPT + n;
#pragma unroll
    for (int c = 0; c < 6; ++c) pts[c] = pb[(size_t)c * NPT];
  }

  for (int q = 0; q < QPB; ++q) {
    const int bs = bs0 + q;
    const int b = bs >> 10;
    const int s = bs & 1023;

    // prefetch next query's gv (consumed next iteration; hidden under C..F)
    const int qn = (q + 1 < QPB) ? (q + 1) : q;
    const int bsn = bs0 + qn;
    float4 gv_next = gq[(size_t)bsn * NK + k];

    // ---- C: layer 1, 9 -> 64 (oc = g32*2 + j) ----
    {
      float in0[9];
      in0[0] = gv.x; in0[1] = gv.y; in0[2] = gv.z;
#pragma unroll
      for (int c = 0; c < 6; ++c) in0[3 + c] = pts[c];
      int oc0 = g32 * 2;
      float acc[2];
#pragma unroll
      for (int j = 0; j < 2; ++j) {
        float a0 = 0.f;
#pragma unroll
        for (int c = 0; c < 9; ++c)
          a0 = fmaf(in0[c], s_w0[(oc0 + j) * 9 + c], a0);
        acc[j] = bnrelu(a0, b0, g0, be0, m0, v0, oc0 + j);
      }
      s_h1[k * 68 + oc0] = acc[0];
      s_h1[k * 68 + oc0 + 1] = acc[1];
    }
    __syncthreads();  // B1

    // prefetch next query's point features (needs gv_next; consumed next iter)
    float pts_next[6];
    {
      int nn = __float_as_int(gv_next.w);
      const float* pbn = points + (size_t)(bsn >> 10) * DIN * NPT + nn;
#pragma unroll
      for (int c = 0; c < 6; ++c) pts_next[c] = pbn[(size_t)c * NPT];
    }

    // ---- D: layer 2, 64 -> 64, h1 -> h2 (oc = g32*2 + j) ----
    {
      int oc0 = g32 * 2;
      float acc[2] = {0.f, 0.f};
      const float4* row = (const float4*)&s_h1[k * 68];
#pragma unroll 4
      for (int c4 = 0; c4 < 16; ++c4) {
        float4 hv = row[c4];
#pragma unroll
        for (int j = 0; j < 2; ++j) {
          float4 wv = *(const float4*)&s_w1[(oc0 + j) * 64 + c4 * 4];
          acc[j] = fmaf(hv.x, wv.x, acc[j]);
          acc[j] = fmaf(hv.y, wv.y, acc[j]);
          acc[j] = fmaf(hv.z, wv.z, acc[j]);
          acc[j] = fmaf(hv.w, wv.w, acc[j]);
        }
      }
#pragma unroll
      for (int j = 0; j < 2; ++j)
        acc[j] = bnrelu(acc[j], b1, g1, be1, m1, v1, oc0 + j);
      s_h2[k * 68 + oc0] = acc[0];
      s_h2[k * 68 + oc0 + 1] = acc[1];
    }
    __syncthreads();  // B2

    // ---- E: layer 3, 64 -> 128, h2 -> u (oc = g32*4 + j); geo tail ----
    {
      int oc0 = g32 * 4;
      float acc[4] = {0.f, 0.f, 0.f, 0.f};
      const float4* row = (const float4*)&s_h2[k * 68];
#pragma unroll 4
      for (int c4 = 0; c4 < 16; ++c4) {
        float4 hv = row[c4];
#pragma unroll
        for (int j = 0; j < 4; ++j) {
          float4 wv = *(const float4*)&s_w2[(oc0 + j) * 64 + c4 * 4];
          acc[j] = fmaf(hv.x, wv.x, acc[j]);
          acc[j] = fmaf(hv.y, wv.y, acc[j]);
          acc[j] = fmaf(hv.z, wv.z, acc[j]);
          acc[j] = fmaf(hv.w, wv.w, acc[j]);
        }
      }
#pragma unroll
      for (int j = 0; j < 4; ++j)
        acc[j] = bnrelu(acc[j], b2, g2, be2, m2, v2, oc0 + j);
      *(float4*)&s_u[k * 132 + oc0] = make_float4(acc[0], acc[1], acc[2], acc[3]);
      if (t < NK) {
        s_u[t * 132 + 128] = gv.x;
        s_u[t * 132 + 129] = gv.y;
        s_u[t * 132 + 130] = gv.z;
        s_u[t * 132 + 131] = 0.f;
      }
    }
    __syncthreads();  // B3

    // ---- F: attention (oc = g32*4 + j), softmax over k in 32-lane halves --
    {
      int oc0 = g32 * 4;
      float acc[4] = {0.f, 0.f, 0.f, 0.f};
      const float4* urow = (const float4*)&s_u[k * 132];
      for (int r4 = 0; r4 < 33; ++r4) {
        float4 uv = urow[r4];
        int r = r4 * 4;
#pragma unroll
        for (int cc = 0; cc < 4; ++cc) {
          int rr = r + cc;
          int arow = (rr < 128) ? (rr + 3) : (rr - 128);  // rr==131 -> a[3]*0
          float uc = (cc == 0) ? uv.x : (cc == 1) ? uv.y : (cc == 2) ? uv.z : uv.w;
          float4 av = *(const float4*)&s_a[arow * 128 + oc0];
          acc[0] = fmaf(uc, av.x, acc[0]);
          acc[1] = fmaf(uc, av.y, acc[1]);
          acc[2] = fmaf(uc, av.z, acc[2]);
          acc[3] = fmaf(uc, av.w, acc[3]);
        }
      }

      float4 cv = *(const float4*)&ceA[(size_t)bs * 128 + oc0];
      float4 hv = *(const float4*)&s_u[k * 132 + oc0];
      float ce[4] = {cv.x, cv.y, cv.z, cv.w};
      float h3[4] = {hv.x, hv.y, hv.z, hv.w};

      float* outb = out1 + (size_t)b * 128 * NS + s;
#pragma unroll
      for (int j = 0; j < 4; ++j) {
        float e = ce[j] - acc[j];
        e = (e >= 0.f) ? e : 0.2f * e;  // leaky relu alpha=0.2
        float mx = e;
#pragma unroll
        for (int off = 16; off > 0; off >>= 1)
          mx = fmaxf(mx, __shfl_xor(mx, off));
        float p = expf(e - mx);
        float num = p * h3[j];
        float den = p;
#pragma unroll
        for (int off = 16; off > 0; off >>= 1) {
          num += __shfl_xor(num, off);
          den += __shfl_xor(den, off);
        }
        if (k == 0) outb[(size_t)(oc0 + j) * NS] = num / den;
      }
    }
    // no trailing barrier needed: F reads only s_u/s_a; next query's s_u
    // writes (E') sit behind B1'+B2'; next C' touches only s_h1 whose
    // readers (this D) finished before B2.

    gv = gv_next;
#pragma unroll
    for (int c = 0; c < 6; ++c) pts[c] = pts_next[c];
  }
}

// ---------------------------------------------------------------------------
extern "C" void kernel_launch(void* const* d_in, const int* in_sizes, int n_in,
                              void* d_out, int out_size, void* d_ws,
                              size_t ws_size, hipStream_t stream) {
  (void)in_sizes; (void)n_in; (void)out_size; (void)ws_size;
  const float* xyz = (const float*)d_in[0];
  const float* points = (const float*)d_in[1];
  const float* w0 = (const float*)d_in[2];
  const float* b0 = (const float*)d_in[3];
  const float* g0 = (const float*)d_in[4];
  const float* be0 = (const float*)d_in[5];
  const float* m0 = (const float*)d_in[6];
  const float* v0 = (const float*)d_in[7];
  const float* w1 = (const float*)d_in[8];
  const float* b1 = (const float*)d_in[9];
  const float* g1 = (const float*)d_in[10];
  const float* be1 = (const float*)d_in[11];
  const float* m1 = (const float*)d_in[12];
  const float* v1 = (const float*)d_in[13];
  const float* w2 = (const float*)d_in[14];
  const float* b2 = (const float*)d_in[15];
  const float* g2 = (const float*)d_in[16];
  const float* be2 = (const float*)d_in[17];
  const float* m2 = (const float*)d_in[18];
  const float* v2 = (const float*)d_in[19];
  const float* a = (const float*)d_in[20];

  float* out0 = (float*)d_out;                  // [B,3,S]
  float* out1 = out0 + (size_t)NB * 3 * NS;     // [B,128,S]

  int* fps = (int*)d_ws;                                        // 32 KB
  float* nxyz = (float*)((char*)d_ws + 32768);                  // 96 KB
  float* ceA = (float*)((char*)d_ws + 131072);                  // 4 MB
  float4* gq = (float4*)((char*)d_ws + 131072 + 4194304);       // 4 MB

  hipFuncSetAttribute(reinterpret_cast<const void*>(mega_kernel),
                      hipFuncAttributeMaxDynamicSharedMemorySize, SMEM_BYTES);

  fps_kernel<<<NB, 1024, 0, stream>>>(xyz, fps, nxyz, out0);
  ballq_kernel<<<NB * NS, 256, 0, stream>>>(xyz, nxyz, gq);
  center_kernel<<<NB * NS, 64, 0, stream>>>(points, nxyz, fps,
      w0, b0, g0, be0, m0, v0, w1, b1, g1, be1, m1, v1,
      w2, b2, g2, be2, m2, v2, a, ceA);
  mega_kernel<<<NB * NS / QPB, MEGA_THREADS, SMEM_BYTES, stream>>>(
      points, ceA, gq,
      w0, b0, g0, be0, m0, v0, w1, b1, g1, be1, m1, v1,
      w2, b2, g2, be2, m2, v2, a, out1);
}

// Round 9
// 2140.323 us; speedup vs baseline: 5.3121x; 5.3121x over previous
//
#include <hip/hip_runtime.h>

#define NB  8
#define NPT 4096
#define NS  1024
#define NK  32
#define DIN 6
#define QPB 32          // queries per mega-block
#define MEGA_THREADS 512

// mega LDS float offsets
#define OFF_A   0            // 131*128 = 16768
#define OFF_W1  16768        // 64*64   = 4096
#define OFF_W2  20864        // 128*64  = 8192
#define OFF_W0  29056        // 64*9    = 576
#define OFF_H1  29632        // 32*68   = 2176
#define OFF_H2  31808        // 32*68   = 2176
#define OFF_U   33984        // 32*132  = 4224
#define FLT_TOT 38208
#define SMEM_BYTES (FLT_TOT * 4)   // 152832 B <= 160 KiB

// ---------------------------------------------------------------------------
__device__ __forceinline__ float bnrelu(float acc, const float* __restrict__ bb,
                                        const float* __restrict__ gg,
                                        const float* __restrict__ be,
                                        const float* __restrict__ mm,
                                        const float* __restrict__ vv, int oc) {
  float t = (acc + bb[oc]) - mm[oc];
  float val = gg[oc] * t * rsqrtf(vv[oc] + 1e-5f) + be[oc];
  return fmaxf(val, 0.0f);
}

// ---------------------------------------------------------------------------
// Wave64 max via DPP + readlane(63). Identity = -1.0f.
// ---------------------------------------------------------------------------
__device__ __forceinline__ float wave64_max(float x) {
  const int NEG1 = 0xbf800000;
  int v;
  v = __builtin_amdgcn_update_dpp(NEG1, __float_as_int(x), 0x111, 0xf, 0xf, false);
  x = fmaxf(x, __int_as_float(v));
  v = __builtin_amdgcn_update_dpp(NEG1, __float_as_int(x), 0x112, 0xf, 0xf, false);
  x = fmaxf(x, __int_as_float(v));
  v = __builtin_amdgcn_update_dpp(NEG1, __float_as_int(x), 0x114, 0xf, 0xf, false);
  x = fmaxf(x, __int_as_float(v));
  v = __builtin_amdgcn_update_dpp(NEG1, __float_as_int(x), 0x118, 0xf, 0xf, false);
  x = fmaxf(x, __int_as_float(v));
  v = __builtin_amdgcn_update_dpp(NEG1, __float_as_int(x), 0x142, 0xa, 0xf, false);
  x = fmaxf(x, __int_as_float(v));
  v = __builtin_amdgcn_update_dpp(NEG1, __float_as_int(x), 0x143, 0xc, 0xf, false);
  x = fmaxf(x, __int_as_float(v));
  return __int_as_float(__builtin_amdgcn_readlane(__float_as_int(x), 63));
}

// ---------------------------------------------------------------------------
// Kernel 1: FPS v6 (kept from R8; 1024 threads x 4 points, 4 waves/SIMD).
// Selection semantics identical to verified v1-v5.
// ---------------------------------------------------------------------------
__global__ __launch_bounds__(1024) void fps_kernel(const float* __restrict__ xyz,
                                                   int* __restrict__ fps_idx,
                                                   float* __restrict__ nxyz,
                                                   float* __restrict__ out0) {
  const int b = blockIdx.x;
  const int t = threadIdx.x;
  const int lane = t & 63, wid = t >> 6;   // wid 0..15
  const float* xb = xyz + (size_t)b * 3 * NPT;

  __shared__ float s_x[NPT], s_y[NPT], s_z[NPT];
  __shared__ __align__(16) float s_red[2][16][2];
  __shared__ float s_ox[NS], s_oy[NS], s_oz[NS];
  __shared__ int s_fi[NS];

  float px[4], py[4], pz[4], dist[4];
  const int base = t * 4;
#pragma unroll
  for (int j = 0; j < 4; ++j) {
    px[j] = xb[base + j];
    py[j] = xb[NPT + base + j];
    pz[j] = xb[2 * NPT + base + j];
    dist[j] = 1e10f;
  }
  for (int i = t; i < NPT; i += 1024) {
    s_x[i] = xb[i];
    s_y[i] = xb[NPT + i];
    s_z[i] = xb[2 * NPT + i];
  }
  __syncthreads();

  int far = 0;
  float cx = xb[0], cy = xb[NPT], cz = xb[2 * NPT];

  for (int s = 0; s < NS; ++s) {
    if (t == 0) {
      s_ox[s] = cx; s_oy[s] = cy; s_oz[s] = cz; s_fi[s] = far;
    }
    float bv = -1.0f;
    int bi = 0;
#pragma unroll
    for (int j = 0; j < 4; ++j) {
      float dx = __fsub_rn(px[j], cx);
      float dy = __fsub_rn(py[j], cy);
      float dz = __fsub_rn(pz[j], cz);
      float d = __fadd_rn(__fadd_rn(__fmul_rn(dx, dx), __fmul_rn(dy, dy)),
                          __fmul_rn(dz, dz));
      float nd = fminf(dist[j], d);
      dist[j] = nd;
      bi = (nd > bv) ? (base + j) : bi;
      bv = fmaxf(bv, nd);
    }
    float mv = wave64_max(bv);
    unsigned long long mmask = __ballot(bv == mv);
    int src = __ffsll(mmask) - 1;
    int wi = __shfl(bi, src);

    const int p = s & 1;
    if (lane == 0) {
      s_red[p][wid][0] = mv;
      s_red[p][wid][1] = __int_as_float(wi);
    }
    __syncthreads();

    // 16-slot left-favored tournament in registers (uniform LDS broadcast)
    float v8[8]; int i8[8];
#pragma unroll
    for (int w = 0; w < 8; ++w) {
      float4 qq = *(const float4*)&s_red[p][w * 2][0];
      bool g = qq.z > qq.x;
      v8[w] = g ? qq.z : qq.x;
      i8[w] = g ? __float_as_int(qq.w) : __float_as_int(qq.y);
    }
#pragma unroll
    for (int off = 1; off < 8; off <<= 1) {
#pragma unroll
      for (int i = 0; i < 8; i += 2 * off) {
        bool g = v8[i + off] > v8[i];
        v8[i] = g ? v8[i + off] : v8[i];
        i8[i] = g ? i8[i + off] : i8[i];
      }
    }
    far = i8[0];
    cx = s_x[far]; cy = s_y[far]; cz = s_z[far];
  }

  __syncthreads();
  for (int i = t; i < NS; i += 1024) {
    float X = s_ox[i], Y = s_oy[i], Z = s_oz[i];
    out0[((size_t)b * 3 + 0) * NS + i] = X;
    out0[((size_t)b * 3 + 1) * NS + i] = Y;
    out0[((size_t)b * 3 + 2) * NS + i] = Z;
    nxyz[((size_t)b * NS + i) * 3 + 0] = X;
    nxyz[((size_t)b * NS + i) * 3 + 1] = Y;
    nxyz[((size_t)b * NS + i) * 3 + 2] = Z;
    fps_idx[b * NS + i] = s_fi[i];
  }
}

// ---------------------------------------------------------------------------
// Kernel 2: center-point MLP + center half of attention scores. (unchanged)
// ---------------------------------------------------------------------------
__global__ __launch_bounds__(64) void center_kernel(
    const float* __restrict__ points, const float* __restrict__ nxyz,
    const int* __restrict__ fps_idx,
    const float* __restrict__ w0, const float* __restrict__ b0,
    const float* __restrict__ g0, const float* __restrict__ be0,
    const float* __restrict__ m0, const float* __restrict__ v0,
    const float* __restrict__ w1, const float* __restrict__ b1,
    const float* __restrict__ g1, const float* __restrict__ be1,
    const float* __restrict__ m1, const float* __restrict__ v1,
    const float* __restrict__ w2, const float* __restrict__ b2,
    const float* __restrict__ g2, const float* __restrict__ be2,
    const float* __restrict__ m2, const float* __restrict__ v2,
    const float* __restrict__ a, float* __restrict__ ceA) {
  const int bs = blockIdx.x;
  const int b = bs >> 10;
  const int t = threadIdx.x;

  __shared__ float ci[9];
  __shared__ float ch1[64];
  __shared__ float ch2[64];
  __shared__ float ch3[128];

  if (t < 9) {
    ci[t] = (t < 3) ? nxyz[(size_t)bs * 3 + t]
                    : points[((size_t)b * DIN + (t - 3)) * NPT + fps_idx[bs]];
  }
  __syncthreads();
  {
    float acc = 0.f;
#pragma unroll
    for (int c = 0; c < 9; ++c) acc = fmaf(ci[c], w0[t * 9 + c], acc);
    ch1[t] = bnrelu(acc, b0, g0, be0, m0, v0, t);
  }
  __syncthreads();
  {
    float acc = 0.f;
#pragma unroll 8
    for (int c = 0; c < 64; ++c) acc = fmaf(ch1[c], w1[t * 64 + c], acc);
    ch2[t] = bnrelu(acc, b1, g1, be1, m1, v1, t);
  }
  __syncthreads();
  for (int oc = t; oc < 128; oc += 64) {
    float acc = 0.f;
#pragma unroll 8
    for (int c = 0; c < 64; ++c) acc = fmaf(ch2[c], w2[oc * 64 + c], acc);
    ch3[oc] = bnrelu(acc, b2, g2, be2, m2, v2, oc);
  }
  __syncthreads();
  for (int oc = t; oc < 128; oc += 64) {
    float acc = 0.f;
#pragma unroll 8
    for (int c = 0; c < 128; ++c) acc = fmaf(ch3[c], a[(3 + c) * 128 + oc], acc);
    ceA[(size_t)bs * 128 + oc] = acc;
  }
}

// ---------------------------------------------------------------------------
// Kernel 3: standalone ball query + gather (unchanged, verified).
// ---------------------------------------------------------------------------
__global__ __launch_bounds__(256) void ballq_kernel(
    const float* __restrict__ xyz, const float* __restrict__ nxyz,
    float4* __restrict__ gq) {
  const int bs = blockIdx.x;
  const int b = bs >> 10;
  const int t = threadIdx.x;
  const int lane = t & 63;
  const int wid = t >> 6;

  __shared__ int s_widx[4][NK];
  __shared__ int s_wc[4];

  const float* xb = xyz + (size_t)b * 3 * NPT;
  const float cx = nxyz[(size_t)bs * 3 + 0];
  const float cy = nxyz[(size_t)bs * 3 + 1];
  const float cz = nxyz[(size_t)bs * 3 + 2];

  {
    const float R2 = (float)(0.15 * 0.15);
    float s2c = __fadd_rn(__fadd_rn(__fmul_rn(cx, cx), __fmul_rn(cy, cy)),
                          __fmul_rn(cz, cz));
    int wcnt = 0;
    for (int g = 0; g < 16; ++g) {
      int n = wid * 1024 + g * 64 + lane;
      float x = xb[n];
      float y = xb[NPT + n];
      float z = xb[2 * NPT + n];
      float pn2 = __fadd_rn(__fadd_rn(__fmul_rn(x, x), __fmul_rn(y, y)),
                            __fmul_rn(z, z));
      float dot = fmaf(cz, z, fmaf(cy, y, __fmul_rn(cx, x)));
      float sqr = __fsub_rn(__fadd_rn(s2c, pn2), __fmul_rn(2.0f, dot));
      bool hit = !(sqr > R2);
      unsigned long long mm = __ballot(hit);
      int pos = wcnt + __popcll(mm & ((1ull << lane) - 1ull));
      if (hit && pos < NK) s_widx[wid][pos] = n;
      wcnt += __popcll(mm);
      if (wcnt >= NK) break;  // wave-uniform
    }
    if (lane == 0) s_wc[wid] = (wcnt < NK) ? wcnt : NK;
  }
  __syncthreads();

  if (t < NK) {
    int c0 = s_wc[0], c1 = s_wc[1], c2 = s_wc[2], c3 = s_wc[3];
    int total = c0 + c1 + c2 + c3;
    int cc[4] = {c0, c1, c2, c3};
    int p = (t < total) ? t : 0;  // pad misses with overall-first hit
    int w = 0;
    while (w < 3 && p >= cc[w]) { p -= cc[w]; ++w; }
    int n = s_widx[w][p];
    float gx = __fsub_rn(xb[n], cx);
    float gy = __fsub_rn(xb[NPT + n], cy);
    float gz = __fsub_rn(xb[2 * NPT + n], cz);
    gq[(size_t)bs * NK + t] = make_float4(gx, gy, gz, __int_as_float(n));
  }
}

// ---------------------------------------------------------------------------
// Kernel 4 (mega v4): R7's verified 512-thread structure + gv/pts prefetch.
// 512 threads (8 waves; no VGPR cliff -- R8's 1024-thread variant forced
// VGPR=64 and spilled 30 GB of scratch). 3 barriers/query, weights in LDS.
// Thread map: k = t&31 (neighbor row), g16 = t>>5 (oc group 0..15).
// ---------------------------------------------------------------------------
__global__ __launch_bounds__(MEGA_THREADS) void mega_kernel(
    const float* __restrict__ points, const float* __restrict__ ceA,
    const float4* __restrict__ gq,
    const float* __restrict__ w0, const float* __restrict__ b0,
    const float* __restrict__ g0, const float* __restrict__ be0,
    const float* __restrict__ m0, const float* __restrict__ v0,
    const float* __restrict__ w1, const float* __restrict__ b1,
    const float* __restrict__ g1, const float* __restrict__ be1,
    const float* __restrict__ m1, const float* __restrict__ v1,
    const float* __restrict__ w2, const float* __restrict__ b2,
    const float* __restrict__ g2, const float* __restrict__ be2,
    const float* __restrict__ m2, const float* __restrict__ v2,
    const float* __restrict__ a, float* __restrict__ out1) {
  extern __shared__ float lds[];
  float* s_a  = lds + OFF_A;
  float* s_w1 = lds + OFF_W1;
  float* s_w2 = lds + OFF_W2;
  float* s_w0 = lds + OFF_W0;
  float* s_h1 = lds + OFF_H1;
  float* s_h2 = lds + OFF_H2;
  float* s_u  = lds + OFF_U;

  const int t = threadIdx.x;
  const int k = t & 31;             // neighbor row
  const int g16 = t >> 5;           // oc group 0..15

  // ---- stage weights into LDS (once per block) ----
  {
    const float4* srcA = (const float4*)a;
    float4* dstA = (float4*)s_a;
    for (int i = t; i < 4192; i += MEGA_THREADS) dstA[i] = srcA[i];
    const float4* src1 = (const float4*)w1;
    float4* dst1 = (float4*)s_w1;
    for (int i = t; i < 1024; i += MEGA_THREADS) dst1[i] = src1[i];
    const float4* src2 = (const float4*)w2;
    float4* dst2 = (float4*)s_w2;
    for (int i = t; i < 2048; i += MEGA_THREADS) dst2[i] = src2[i];
    for (int i = t; i < 576; i += MEGA_THREADS) s_w0[i] = w0[i];
  }
  __syncthreads();

  const int bs0 = blockIdx.x * QPB;

  // prologue: q=0's neighbor record + point features
  float4 gv = gq[(size_t)bs0 * NK + k];
  float pts[6];
  {
    int n = __float_as_int(gv.w);
    const float* pb = points + (size_t)(bs0 >> 10) * DIN * NPT + n;
#pragma unroll
    for (int c = 0; c < 6; ++c) pts[c] = pb[(size_t)c * NPT];
  }

  for (int q = 0; q < QPB; ++q) {
    const int bs = bs0 + q;
    const int b = bs >> 10;
    const int s = bs & 1023;

    // prefetch next query's gv (consumed next iter; hidden under C..F)
    const int qn = (q + 1 < QPB) ? (q + 1) : q;
    const int bsn = bs0 + qn;
    float4 gv_next = gq[(size_t)bsn * NK + k];

    // ---- C: layer 1, 9 -> 64 (oc = g16*4 + j) ----
    {
      float in0[9];
      in0[0] = gv.x; in0[1] = gv.y; in0[2] = gv.z;
#pragma unroll
      for (int c = 0; c < 6; ++c) in0[3 + c] = pts[c];
      int oc0 = g16 * 4;
      float acc[4];
#pragma unroll
      for (int j = 0; j < 4; ++j) {
        float a0 = 0.f;
#pragma unroll
        for (int c = 0; c < 9; ++c)
          a0 = fmaf(in0[c], s_w0[(oc0 + j) * 9 + c], a0);
        acc[j] = bnrelu(a0, b0, g0, be0, m0, v0, oc0 + j);
      }
      *(float4*)&s_h1[k * 68 + oc0] = make_float4(acc[0], acc[1], acc[2], acc[3]);
    }
    __syncthreads();  // B1

    // prefetch next query's point features (needs gv_next; consumed next iter)
    float pts_next[6];
    {
      int nn = __float_as_int(gv_next.w);
      const float* pbn = points + (size_t)(bsn >> 10) * DIN * NPT + nn;
#pragma unroll
      for (int c = 0; c < 6; ++c) pts_next[c] = pbn[(size_t)c * NPT];
    }

    // ---- D: layer 2, 64 -> 64, h1 -> h2 ----
    {
      int oc0 = g16 * 4;
      float acc[4] = {0.f, 0.f, 0.f, 0.f};
      const float4* row = (const float4*)&s_h1[k * 68];
#pragma unroll 4
      for (int c4 = 0; c4 < 16; ++c4) {
        float4 hv = row[c4];
#pragma unroll
        for (int j = 0; j < 4; ++j) {
          float4 wv = *(const float4*)&s_w1[(oc0 + j) * 64 + c4 * 4];
          acc[j] = fmaf(hv.x, wv.x, acc[j]);
          acc[j] = fmaf(hv.y, wv.y, acc[j]);
          acc[j] = fmaf(hv.z, wv.z, acc[j]);
          acc[j] = fmaf(hv.w, wv.w, acc[j]);
        }
      }
#pragma unroll
      for (int j = 0; j < 4; ++j)
        acc[j] = bnrelu(acc[j], b1, g1, be1, m1, v1, oc0 + j);
      *(float4*)&s_h2[k * 68 + oc0] = make_float4(acc[0], acc[1], acc[2], acc[3]);
    }
    __syncthreads();  // B2

    // ---- E: layer 3, 64 -> 128, h2 -> u; geo tail from registers ----
    {
      int oc0 = g16 * 8;
      float acc[8] = {0.f, 0.f, 0.f, 0.f, 0.f, 0.f, 0.f, 0.f};
      const float4* row = (const float4*)&s_h2[k * 68];
#pragma unroll 2
      for (int c4 = 0; c4 < 16; ++c4) {
        float4 hv = row[c4];
#pragma unroll
        for (int j = 0; j < 8; ++j) {
          float4 wv = *(const float4*)&s_w2[(oc0 + j) * 64 + c4 * 4];
          acc[j] = fmaf(hv.x, wv.x, acc[j]);
          acc[j] = fmaf(hv.y, wv.y, acc[j]);
          acc[j] = fmaf(hv.z, wv.z, acc[j]);
          acc[j] = fmaf(hv.w, wv.w, acc[j]);
        }
      }
#pragma unroll
      for (int j = 0; j < 8; ++j)
        acc[j] = bnrelu(acc[j], b2, g2, be2, m2, v2, oc0 + j);
      float4* orow = (float4*)&s_u[k * 132 + oc0];
      orow[0] = make_float4(acc[0], acc[1], acc[2], acc[3]);
      orow[1] = make_float4(acc[4], acc[5], acc[6], acc[7]);
      if (t < NK) {
        s_u[t * 132 + 128] = gv.x;
        s_u[t * 132 + 129] = gv.y;
        s_u[t * 132 + 130] = gv.z;
        s_u[t * 132 + 131] = 0.f;
      }
    }
    __syncthreads();  // B3

    // ---- F: attention (oc = g16*8 + j), softmax over k in 32-lane halves --
    {
      int oc0 = g16 * 8;
      float acc[8] = {0.f, 0.f, 0.f, 0.f, 0.f, 0.f, 0.f, 0.f};
      const float4* urow = (const float4*)&s_u[k * 132];
      for (int r4 = 0; r4 < 33; ++r4) {
        float4 uv = urow[r4];
        int r = r4 * 4;
#pragma unroll
        for (int cc = 0; cc < 4; ++cc) {
          int rr = r + cc;
          int arow = (rr < 128) ? (rr + 3) : (rr - 128);  // rr==131 -> a[3]*0
          float uc = (cc == 0) ? uv.x : (cc == 1) ? uv.y : (cc == 2) ? uv.z : uv.w;
          const float4* ap = (const float4*)&s_a[arow * 128 + oc0];
          float4 av0 = ap[0], av1 = ap[1];
          acc[0] = fmaf(uc, av0.x, acc[0]);
          acc[1] = fmaf(uc, av0.y, acc[1]);
          acc[2] = fmaf(uc, av0.z, acc[2]);
          acc[3] = fmaf(uc, av0.w, acc[3]);
          acc[4] = fmaf(uc, av1.x, acc[4]);
          acc[5] = fmaf(uc, av1.y, acc[5]);
          acc[6] = fmaf(uc, av1.z, acc[6]);
          acc[7] = fmaf(uc, av1.w, acc[7]);
        }
      }

      float ce[8], h3[8];
      {
        float4 cv0 = *(const float4*)&ceA[(size_t)bs * 128 + oc0];
        float4 cv1 = *(const float4*)&ceA[(size_t)bs * 128 + oc0 + 4];
        ce[0] = cv0.x; ce[1] = cv0.y; ce[2] = cv0.z; ce[3] = cv0.w;
        ce[4] = cv1.x; ce[5] = cv1.y; ce[6] = cv1.z; ce[7] = cv1.w;
        float4 hv0 = *(const float4*)&s_u[k * 132 + oc0];
        float4 hv1 = *(const float4*)&s_u[k * 132 + oc0 + 4];
        h3[0] = hv0.x; h3[1] = hv0.y; h3[2] = hv0.z; h3[3] = hv0.w;
        h3[4] = hv1.x; h3[5] = hv1.y; h3[6] = hv1.z; h3[7] = hv1.w;
      }

      float* outb = out1 + (size_t)b * 128 * NS + s;
#pragma unroll
      for (int j = 0; j < 8; ++j) {
        float e = ce[j] - acc[j];
        e = (e >= 0.f) ? e : 0.2f * e;  // leaky relu alpha=0.2
        float mx = e;
#pragma unroll
        for (int off = 16; off > 0; off >>= 1)
          mx = fmaxf(mx, __shfl_xor(mx, off));
        float p = expf(e - mx);
        float num = p * h3[j];
        float den = p;
#pragma unroll
        for (int off = 16; off > 0; off >>= 1) {
          num += __shfl_xor(num, off);
          den += __shfl_xor(den, off);
        }
        if (k == 0) outb[(size_t)(oc0 + j) * NS] = num / den;
      }
    }
    // no trailing barrier needed: F reads only s_u/s_a; next query's s_u
    // writes (E') sit behind B1'+B2'; next C' touches only s_h1 whose
    // readers (this D) finished before B2.

    gv = gv_next;
#pragma unroll
    for (int c = 0; c < 6; ++c) pts[c] = pts_next[c];
  }
}

// ---------------------------------------------------------------------------
extern "C" void kernel_launch(void* const* d_in, const int* in_sizes, int n_in,
                              void* d_out, int out_size, void* d_ws,
                              size_t ws_size, hipStream_t stream) {
  (void)in_sizes; (void)n_in; (void)out_size; (void)ws_size;
  const float* xyz = (const float*)d_in[0];
  const float* points = (const float*)d_in[1];
  const float* w0 = (const float*)d_in[2];
  const float* b0 = (const float*)d_in[3];
  const float* g0 = (const float*)d_in[4];
  const float* be0 = (const float*)d_in[5];
  const float* m0 = (const float*)d_in[6];
  const float* v0 = (const float*)d_in[7];
  const float* w1 = (const float*)d_in[8];
  const float* b1 = (const float*)d_in[9];
  const float* g1 = (const float*)d_in[10];
  const float* be1 = (const float*)d_in[11];
  const float* m1 = (const float*)d_in[12];
  const float* v1 = (const float*)d_in[13];
  const float* w2 = (const float*)d_in[14];
  const float* b2 = (const float*)d_in[15];
  const float* g2 = (const float*)d_in[16];
  const float* be2 = (const float*)d_in[17];
  const float* m2 = (const float*)d_in[18];
  const float* v2 = (const float*)d_in[19];
  const float* a = (const float*)d_in[20];

  float* out0 = (float*)d_out;                  // [B,3,S]
  float* out1 = out0 + (size_t)NB * 3 * NS;     // [B,128,S]

  int* fps = (int*)d_ws;                                        // 32 KB
  float* nxyz = (float*)((char*)d_ws + 32768);                  // 96 KB
  float* ceA = (float*)((char*)d_ws + 131072);                  // 4 MB
  float4* gq = (float4*)((char*)d_ws + 131072 + 4194304);       // 4 MB

  hipFuncSetAttribute(reinterpret_cast<const void*>(mega_kernel),
                      hipFuncAttributeMaxDynamicSharedMemorySize, SMEM_BYTES);

  fps_kernel<<<NB, 1024, 0, stream>>>(xyz, fps, nxyz, out0);
  ballq_kernel<<<NB * NS, 256, 0, stream>>>(xyz, nxyz, gq);
  center_kernel<<<NB * NS, 64, 0, stream>>>(points, nxyz, fps,
      w0, b0, g0, be0, m0, v0, w1, b1, g1, be1, m1, v1,
      w2, b2, g2, be2, m2, v2, a, ceA);
  mega_kernel<<<NB * NS / QPB, MEGA_THREADS, SMEM_BYTES, stream>>>(
      points, ceA, gq,
      w0, b0, g0, be0, m0, v0, w1, b1, g1, be1, m1, v1,
      w2, b2, g2, be2, m2, v2, a, out1);
}

// Round 10
// 1131.932 us; speedup vs baseline: 10.0444x; 1.8909x over previous
//
#include <hip/hip_runtime.h>

#define NB  8
#define NPT 4096
#define NS  1024
#define NK  32
#define DIN 6
#define QPB 32          // queries per mega-block
#define MEGA_THREADS 512

// mega LDS float offsets
#define OFF_A   0            // 131*128 = 16768
#define OFF_W1  16768        // 64*64   = 4096
#define OFF_W2  20864        // 128*64  = 8192
#define OFF_W0  29056        // 64*9    = 576
#define OFF_H1  29632        // 32*68   = 2176
#define OFF_H2  31808        // 32*68   = 2176
#define OFF_U   33984        // 32*132  = 4224
#define FLT_TOT 38208
#define SMEM_BYTES (FLT_TOT * 4)   // 152832 B <= 160 KiB

// ---------------------------------------------------------------------------
__device__ __forceinline__ float bnrelu(float acc, const float* __restrict__ bb,
                                        const float* __restrict__ gg,
                                        const float* __restrict__ be,
                                        const float* __restrict__ mm,
                                        const float* __restrict__ vv, int oc) {
  float t = (acc + bb[oc]) - mm[oc];
  float val = gg[oc] * t * rsqrtf(vv[oc] + 1e-5f) + be[oc];
  return fmaxf(val, 0.0f);
}

// ---------------------------------------------------------------------------
// Wave64 max via DPP + readlane(63). Identity = -1.0f.
// ---------------------------------------------------------------------------
__device__ __forceinline__ float wave64_max(float x) {
  const int NEG1 = 0xbf800000;
  int v;
  v = __builtin_amdgcn_update_dpp(NEG1, __float_as_int(x), 0x111, 0xf, 0xf, false);
  x = fmaxf(x, __int_as_float(v));
  v = __builtin_amdgcn_update_dpp(NEG1, __float_as_int(x), 0x112, 0xf, 0xf, false);
  x = fmaxf(x, __int_as_float(v));
  v = __builtin_amdgcn_update_dpp(NEG1, __float_as_int(x), 0x114, 0xf, 0xf, false);
  x = fmaxf(x, __int_as_float(v));
  v = __builtin_amdgcn_update_dpp(NEG1, __float_as_int(x), 0x118, 0xf, 0xf, false);
  x = fmaxf(x, __int_as_float(v));
  v = __builtin_amdgcn_update_dpp(NEG1, __float_as_int(x), 0x142, 0xa, 0xf, false);
  x = fmaxf(x, __int_as_float(v));
  v = __builtin_amdgcn_update_dpp(NEG1, __float_as_int(x), 0x143, 0xc, 0xf, false);
  x = fmaxf(x, __int_as_float(v));
  return __int_as_float(__builtin_amdgcn_readlane(__float_as_int(x), 63));
}

// ---------------------------------------------------------------------------
// Kernel 1: FPS — REVERTED to the verified 512-thread v5 (659 us, VGPR 52).
// R9's 1024-thread variant hit a compiler VGPR cliff (VGPR=20 -> 1493 us).
// ---------------------------------------------------------------------------
__global__ __launch_bounds__(512) void fps_kernel(const float* __restrict__ xyz,
                                                  int* __restrict__ fps_idx,
                                                  float* __restrict__ nxyz,
                                                  float* __restrict__ out0) {
  const int b = blockIdx.x;
  const int t = threadIdx.x;
  const int lane = t & 63, wid = t >> 6;
  const float* xb = xyz + (size_t)b * 3 * NPT;

  __shared__ float s_x[NPT], s_y[NPT], s_z[NPT];
  __shared__ __align__(16) float s_red[2][8][2];
  __shared__ float s_ox[NS], s_oy[NS], s_oz[NS];
  __shared__ int s_fi[NS];

  float px[8], py[8], pz[8], dist[8];
  const int base = t * 8;
#pragma unroll
  for (int j = 0; j < 8; ++j) {
    px[j] = xb[base + j];
    py[j] = xb[NPT + base + j];
    pz[j] = xb[2 * NPT + base + j];
    dist[j] = 1e10f;
  }
  for (int i = t; i < NPT; i += 512) {
    s_x[i] = xb[i];
    s_y[i] = xb[NPT + i];
    s_z[i] = xb[2 * NPT + i];
  }
  __syncthreads();

  int far = 0;
  float cx = xb[0], cy = xb[NPT], cz = xb[2 * NPT];

  for (int s = 0; s < NS; ++s) {
    if (t == 0) {
      s_ox[s] = cx; s_oy[s] = cy; s_oz[s] = cz; s_fi[s] = far;
    }
    float bv = -1.0f;
    int bi = 0;
#pragma unroll
    for (int j = 0; j < 8; ++j) {
      float dx = __fsub_rn(px[j], cx);
      float dy = __fsub_rn(py[j], cy);
      float dz = __fsub_rn(pz[j], cz);
      float d = __fadd_rn(__fadd_rn(__fmul_rn(dx, dx), __fmul_rn(dy, dy)),
                          __fmul_rn(dz, dz));
      float nd = fminf(dist[j], d);
      dist[j] = nd;
      bi = (nd > bv) ? (base + j) : bi;
      bv = fmaxf(bv, nd);
    }
    float mv = wave64_max(bv);
    unsigned long long mmask = __ballot(bv == mv);
    int src = __ffsll(mmask) - 1;
    int wi = __shfl(bi, src);

    const int p = s & 1;
    if (lane == 0) {
      s_red[p][wid][0] = mv;
      s_red[p][wid][1] = __int_as_float(wi);
    }
    __syncthreads();

    float4 q0 = *(const float4*)&s_red[p][0][0];
    float4 q1 = *(const float4*)&s_red[p][2][0];
    float4 q2 = *(const float4*)&s_red[p][4][0];
    float4 q3 = *(const float4*)&s_red[p][6][0];
    // tournament: right side wins only on strict > => first max overall
    float va, vb, vc, vd; int ia, ib, ic, id;
    { bool g = q0.z > q0.x; va = g ? q0.z : q0.x;
      ia = g ? __float_as_int(q0.w) : __float_as_int(q0.y); }
    { bool g = q1.z > q1.x; vb = g ? q1.z : q1.x;
      ib = g ? __float_as_int(q1.w) : __float_as_int(q1.y); }
    { bool g = q2.z > q2.x; vc = g ? q2.z : q2.x;
      ic = g ? __float_as_int(q2.w) : __float_as_int(q2.y); }
    { bool g = q3.z > q3.x; vd = g ? q3.z : q3.x;
      id = g ? __float_as_int(q3.w) : __float_as_int(q3.y); }
    { bool g = vb > va; va = g ? vb : va; ia = g ? ib : ia; }
    { bool g = vd > vc; vc = g ? vd : vc; ic = g ? id : ic; }
    { bool g = vc > va; va = g ? vc : va; ia = g ? ic : ia; }
    far = ia;
    cx = s_x[far]; cy = s_y[far]; cz = s_z[far];
  }

  __syncthreads();
  for (int i = t; i < NS; i += 512) {
    float X = s_ox[i], Y = s_oy[i], Z = s_oz[i];
    out0[((size_t)b * 3 + 0) * NS + i] = X;
    out0[((size_t)b * 3 + 1) * NS + i] = Y;
    out0[((size_t)b * 3 + 2) * NS + i] = Z;
    nxyz[((size_t)b * NS + i) * 3 + 0] = X;
    nxyz[((size_t)b * NS + i) * 3 + 1] = Y;
    nxyz[((size_t)b * NS + i) * 3 + 2] = Z;
    fps_idx[b * NS + i] = s_fi[i];
  }
}

// ---------------------------------------------------------------------------
// Kernel 2: center-point MLP + center half of attention scores. (unchanged)
// ---------------------------------------------------------------------------
__global__ __launch_bounds__(64) void center_kernel(
    const float* __restrict__ points, const float* __restrict__ nxyz,
    const int* __restrict__ fps_idx,
    const float* __restrict__ w0, const float* __restrict__ b0,
    const float* __restrict__ g0, const float* __restrict__ be0,
    const float* __restrict__ m0, const float* __restrict__ v0,
    const float* __restrict__ w1, const float* __restrict__ b1,
    const float* __restrict__ g1, const float* __restrict__ be1,
    const float* __restrict__ m1, const float* __restrict__ v1,
    const float* __restrict__ w2, const float* __restrict__ b2,
    const float* __restrict__ g2, const float* __restrict__ be2,
    const float* __restrict__ m2, const float* __restrict__ v2,
    const float* __restrict__ a, float* __restrict__ ceA) {
  const int bs = blockIdx.x;
  const int b = bs >> 10;
  const int t = threadIdx.x;

  __shared__ float ci[9];
  __shared__ float ch1[64];
  __shared__ float ch2[64];
  __shared__ float ch3[128];

  if (t < 9) {
    ci[t] = (t < 3) ? nxyz[(size_t)bs * 3 + t]
                    : points[((size_t)b * DIN + (t - 3)) * NPT + fps_idx[bs]];
  }
  __syncthreads();
  {
    float acc = 0.f;
#pragma unroll
    for (int c = 0; c < 9; ++c) acc = fmaf(ci[c], w0[t * 9 + c], acc);
    ch1[t] = bnrelu(acc, b0, g0, be0, m0, v0, t);
  }
  __syncthreads();
  {
    float acc = 0.f;
#pragma unroll 8
    for (int c = 0; c < 64; ++c) acc = fmaf(ch1[c], w1[t * 64 + c], acc);
    ch2[t] = bnrelu(acc, b1, g1, be1, m1, v1, t);
  }
  __syncthreads();
  for (int oc = t; oc < 128; oc += 64) {
    float acc = 0.f;
#pragma unroll 8
    for (int c = 0; c < 64; ++c) acc = fmaf(ch2[c], w2[oc * 64 + c], acc);
    ch3[oc] = bnrelu(acc, b2, g2, be2, m2, v2, oc);
  }
  __syncthreads();
  for (int oc = t; oc < 128; oc += 64) {
    float acc = 0.f;
#pragma unroll 8
    for (int c = 0; c < 128; ++c) acc = fmaf(ch3[c], a[(3 + c) * 128 + oc], acc);
    ceA[(size_t)bs * 128 + oc] = acc;
  }
}

// ---------------------------------------------------------------------------
// Kernel 3: standalone ball query + gather (unchanged, verified).
// ---------------------------------------------------------------------------
__global__ __launch_bounds__(256) void ballq_kernel(
    const float* __restrict__ xyz, const float* __restrict__ nxyz,
    float4* __restrict__ gq) {
  const int bs = blockIdx.x;
  const int b = bs >> 10;
  const int t = threadIdx.x;
  const int lane = t & 63;
  const int wid = t >> 6;

  __shared__ int s_widx[4][NK];
  __shared__ int s_wc[4];

  const float* xb = xyz + (size_t)b * 3 * NPT;
  const float cx = nxyz[(size_t)bs * 3 + 0];
  const float cy = nxyz[(size_t)bs * 3 + 1];
  const float cz = nxyz[(size_t)bs * 3 + 2];

  {
    const float R2 = (float)(0.15 * 0.15);
    float s2c = __fadd_rn(__fadd_rn(__fmul_rn(cx, cx), __fmul_rn(cy, cy)),
                          __fmul_rn(cz, cz));
    int wcnt = 0;
    for (int g = 0; g < 16; ++g) {
      int n = wid * 1024 + g * 64 + lane;
      float x = xb[n];
      float y = xb[NPT + n];
      float z = xb[2 * NPT + n];
      float pn2 = __fadd_rn(__fadd_rn(__fmul_rn(x, x), __fmul_rn(y, y)),
                            __fmul_rn(z, z));
      float dot = fmaf(cz, z, fmaf(cy, y, __fmul_rn(cx, x)));
      float sqr = __fsub_rn(__fadd_rn(s2c, pn2), __fmul_rn(2.0f, dot));
      bool hit = !(sqr > R2);
      unsigned long long mm = __ballot(hit);
      int pos = wcnt + __popcll(mm & ((1ull << lane) - 1ull));
      if (hit && pos < NK) s_widx[wid][pos] = n;
      wcnt += __popcll(mm);
      if (wcnt >= NK) break;  // wave-uniform
    }
    if (lane == 0) s_wc[wid] = (wcnt < NK) ? wcnt : NK;
  }
  __syncthreads();

  if (t < NK) {
    int c0 = s_wc[0], c1 = s_wc[1], c2 = s_wc[2], c3 = s_wc[3];
    int total = c0 + c1 + c2 + c3;
    int cc[4] = {c0, c1, c2, c3};
    int p = (t < total) ? t : 0;  // pad misses with overall-first hit
    int w = 0;
    while (w < 3 && p >= cc[w]) { p -= cc[w]; ++w; }
    int n = s_widx[w][p];
    float gx = __fsub_rn(xb[n], cx);
    float gy = __fsub_rn(xb[NPT + n], cy);
    float gz = __fsub_rn(xb[2 * NPT + n], cz);
    gq[(size_t)bs * NK + t] = make_float4(gx, gy, gz, __int_as_float(n));
  }
}

// ---------------------------------------------------------------------------
// Kernel 4 (mega v5): 512 threads; D/E/F remapped to (kk = t&15, gg = t>>4,
// TWO k-rows per thread) so each weight/a b128 read feeds 2 k-row FMA groups:
// LDS instructions per query per thread D 80->64, E 144->96, F 297->198
// (-31%); FMA count unchanged. Softmax over 32 k = pair-combine + 16-lane
// shfl_xor tree (offsets stay inside the 16-lane group). C phase, prefetch,
// 3-barrier structure, no-trailing-barrier proof unchanged.
// ---------------------------------------------------------------------------
__global__ __launch_bounds__(MEGA_THREADS) void mega_kernel(
    const float* __restrict__ points, const float* __restrict__ ceA,
    const float4* __restrict__ gq,
    const float* __restrict__ w0, const float* __restrict__ b0,
    const float* __restrict__ g0, const float* __restrict__ be0,
    const float* __restrict__ m0, const float* __restrict__ v0,
    const float* __restrict__ w1, const float* __restrict__ b1,
    const float* __restrict__ g1, const float* __restrict__ be1,
    const float* __restrict__ m1, const float* __restrict__ v1,
    const float* __restrict__ w2, const float* __restrict__ b2,
    const float* __restrict__ g2, const float* __restrict__ be2,
    const float* __restrict__ m2, const float* __restrict__ v2,
    const float* __restrict__ a, float* __restrict__ out1) {
  extern __shared__ float lds[];
  float* s_a  = lds + OFF_A;
  float* s_w1 = lds + OFF_W1;
  float* s_w2 = lds + OFF_W2;
  float* s_w0 = lds + OFF_W0;
  float* s_h1 = lds + OFF_H1;
  float* s_h2 = lds + OFF_H2;
  float* s_u  = lds + OFF_U;

  const int t = threadIdx.x;
  const int k = t & 31;             // C-phase neighbor row
  const int g16 = t >> 5;           // C-phase oc group 0..15
  const int kk = t & 15;            // D/E/F k base (rows kk, kk+16)
  const int gg = t >> 4;            // D/E/F oc group 0..31

  // ---- stage weights into LDS (once per block) ----
  {
    const float4* srcA = (const float4*)a;
    float4* dstA = (float4*)s_a;
    for (int i = t; i < 4192; i += MEGA_THREADS) dstA[i] = srcA[i];
    const float4* src1 = (const float4*)w1;
    float4* dst1 = (float4*)s_w1;
    for (int i = t; i < 1024; i += MEGA_THREADS) dst1[i] = src1[i];
    const float4* src2 = (const float4*)w2;
    float4* dst2 = (float4*)s_w2;
    for (int i = t; i < 2048; i += MEGA_THREADS) dst2[i] = src2[i];
    for (int i = t; i < 576; i += MEGA_THREADS) s_w0[i] = w0[i];
  }
  __syncthreads();

  const int bs0 = blockIdx.x * QPB;

  // prologue: q=0's neighbor record + point features (C-phase mapping, k)
  float4 gv = gq[(size_t)bs0 * NK + k];
  float pts[6];
  {
    int n = __float_as_int(gv.w);
    const float* pb = points + (size_t)(bs0 >> 10) * DIN * NPT + n;
#pragma unroll
    for (int c = 0; c < 6; ++c) pts[c] = pb[(size_t)c * NPT];
  }

  for (int q = 0; q < QPB; ++q) {
    const int bs = bs0 + q;
    const int b = bs >> 10;
    const int s = bs & 1023;

    const int qn = (q + 1 < QPB) ? (q + 1) : q;
    const int bsn = bs0 + qn;
    float4 gv_next = gq[(size_t)bsn * NK + k];

    // ---- C: layer 1, 9 -> 64 (k = t&31, oc = g16*4 + j) ----
    {
      float in0[9];
      in0[0] = gv.x; in0[1] = gv.y; in0[2] = gv.z;
#pragma unroll
      for (int c = 0; c < 6; ++c) in0[3 + c] = pts[c];
      int oc0 = g16 * 4;
      float acc[4];
#pragma unroll
      for (int j = 0; j < 4; ++j) {
        float a0 = 0.f;
#pragma unroll
        for (int c = 0; c < 9; ++c)
          a0 = fmaf(in0[c], s_w0[(oc0 + j) * 9 + c], a0);
        acc[j] = bnrelu(a0, b0, g0, be0, m0, v0, oc0 + j);
      }
      *(float4*)&s_h1[k * 68 + oc0] = make_float4(acc[0], acc[1], acc[2], acc[3]);
    }
    __syncthreads();  // B1

    // prefetch next query's point features
    float pts_next[6];
    {
      int nn = __float_as_int(gv_next.w);
      const float* pbn = points + (size_t)(bsn >> 10) * DIN * NPT + nn;
#pragma unroll
      for (int c = 0; c < 6; ++c) pts_next[c] = pbn[(size_t)c * NPT];
    }

    // ---- D: layer 2, 64 -> 64; rows kk & kk+16, oc = gg*2 + j ----
    {
      int oc0 = gg * 2;
      float a0[2] = {0.f, 0.f}, a1[2] = {0.f, 0.f};
      const float4* row0 = (const float4*)&s_h1[kk * 68];
      const float4* row1 = (const float4*)&s_h1[(kk + 16) * 68];
#pragma unroll 4
      for (int c4 = 0; c4 < 16; ++c4) {
        float4 h0 = row0[c4];
        float4 h1 = row1[c4];
#pragma unroll
        for (int j = 0; j < 2; ++j) {
          float4 wv = *(const float4*)&s_w1[(oc0 + j) * 64 + c4 * 4];
          a0[j] = fmaf(h0.x, wv.x, a0[j]);
          a0[j] = fmaf(h0.y, wv.y, a0[j]);
          a0[j] = fmaf(h0.z, wv.z, a0[j]);
          a0[j] = fmaf(h0.w, wv.w, a0[j]);
          a1[j] = fmaf(h1.x, wv.x, a1[j]);
          a1[j] = fmaf(h1.y, wv.y, a1[j]);
          a1[j] = fmaf(h1.z, wv.z, a1[j]);
          a1[j] = fmaf(h1.w, wv.w, a1[j]);
        }
      }
#pragma unroll
      for (int j = 0; j < 2; ++j) {
        a0[j] = bnrelu(a0[j], b1, g1, be1, m1, v1, oc0 + j);
        a1[j] = bnrelu(a1[j], b1, g1, be1, m1, v1, oc0 + j);
      }
      s_h2[kk * 68 + oc0] = a0[0];
      s_h2[kk * 68 + oc0 + 1] = a0[1];
      s_h2[(kk + 16) * 68 + oc0] = a1[0];
      s_h2[(kk + 16) * 68 + oc0 + 1] = a1[1];
    }
    __syncthreads();  // B2

    // ---- E: layer 3, 64 -> 128; rows kk & kk+16, oc = gg*4 + j ----
    {
      int oc0 = gg * 4;
      float a0[4] = {0.f, 0.f, 0.f, 0.f}, a1[4] = {0.f, 0.f, 0.f, 0.f};
      const float4* row0 = (const float4*)&s_h2[kk * 68];
      const float4* row1 = (const float4*)&s_h2[(kk + 16) * 68];
#pragma unroll 4
      for (int c4 = 0; c4 < 16; ++c4) {
        float4 h0 = row0[c4];
        float4 h1 = row1[c4];
#pragma unroll
        for (int j = 0; j < 4; ++j) {
          float4 wv = *(const float4*)&s_w2[(oc0 + j) * 64 + c4 * 4];
          a0[j] = fmaf(h0.x, wv.x, a0[j]);
          a0[j] = fmaf(h0.y, wv.y, a0[j]);
          a0[j] = fmaf(h0.z, wv.z, a0[j]);
          a0[j] = fmaf(h0.w, wv.w, a0[j]);
          a1[j] = fmaf(h1.x, wv.x, a1[j]);
          a1[j] = fmaf(h1.y, wv.y, a1[j]);
          a1[j] = fmaf(h1.z, wv.z, a1[j]);
          a1[j] = fmaf(h1.w, wv.w, a1[j]);
        }
      }
#pragma unroll
      for (int j = 0; j < 4; ++j) {
        a0[j] = bnrelu(a0[j], b2, g2, be2, m2, v2, oc0 + j);
        a1[j] = bnrelu(a1[j], b2, g2, be2, m2, v2, oc0 + j);
      }
      *(float4*)&s_u[kk * 132 + oc0] = make_float4(a0[0], a0[1], a0[2], a0[3]);
      *(float4*)&s_u[(kk + 16) * 132 + oc0] =
          make_float4(a1[0], a1[1], a1[2], a1[3]);
      if (t < NK) {
        s_u[t * 132 + 128] = gv.x;
        s_u[t * 132 + 129] = gv.y;
        s_u[t * 132 + 130] = gv.z;
        s_u[t * 132 + 131] = 0.f;
      }
    }
    __syncthreads();  // B3

    // ---- F: attention; rows kk & kk+16, oc = gg*4 + j; softmax over 32 k
    //      = pair-combine + 16-lane shfl_xor tree ----
    {
      int oc0 = gg * 4;
      float a0[4] = {0.f, 0.f, 0.f, 0.f}, a1[4] = {0.f, 0.f, 0.f, 0.f};
      const float4* urow0 = (const float4*)&s_u[kk * 132];
      const float4* urow1 = (const float4*)&s_u[(kk + 16) * 132];
      for (int r4 = 0; r4 < 33; ++r4) {
        float4 uv0 = urow0[r4];
        float4 uv1 = urow1[r4];
        int r = r4 * 4;
#pragma unroll
        for (int cc = 0; cc < 4; ++cc) {
          int rr = r + cc;
          int arow = (rr < 128) ? (rr + 3) : (rr - 128);  // rr==131 -> a[3]*0
          float uc0 = (cc == 0) ? uv0.x : (cc == 1) ? uv0.y : (cc == 2) ? uv0.z : uv0.w;
          float uc1 = (cc == 0) ? uv1.x : (cc == 1) ? uv1.y : (cc == 2) ? uv1.z : uv1.w;
          float4 av = *(const float4*)&s_a[arow * 128 + oc0];
          a0[0] = fmaf(uc0, av.x, a0[0]);
          a0[1] = fmaf(uc0, av.y, a0[1]);
          a0[2] = fmaf(uc0, av.z, a0[2]);
          a0[3] = fmaf(uc0, av.w, a0[3]);
          a1[0] = fmaf(uc1, av.x, a1[0]);
          a1[1] = fmaf(uc1, av.y, a1[1]);
          a1[2] = fmaf(uc1, av.z, a1[2]);
          a1[3] = fmaf(uc1, av.w, a1[3]);
        }
      }

      float4 cv = *(const float4*)&ceA[(size_t)bs * 128 + oc0];
      float4 h0v = *(const float4*)&s_u[kk * 132 + oc0];
      float4 h1v = *(const float4*)&s_u[(kk + 16) * 132 + oc0];
      float ce[4] = {cv.x, cv.y, cv.z, cv.w};
      float h0[4] = {h0v.x, h0v.y, h0v.z, h0v.w};
      float h1[4] = {h1v.x, h1v.y, h1v.z, h1v.w};

      float* outb = out1 + (size_t)b * 128 * NS + s;
#pragma unroll
      for (int j = 0; j < 4; ++j) {
        float e0 = ce[j] - a0[j];
        float e1 = ce[j] - a1[j];
        e0 = (e0 >= 0.f) ? e0 : 0.2f * e0;  // leaky relu alpha=0.2
        e1 = (e1 >= 0.f) ? e1 : 0.2f * e1;
        float mx = fmaxf(e0, e1);
#pragma unroll
        for (int off = 8; off > 0; off >>= 1)
          mx = fmaxf(mx, __shfl_xor(mx, off));   // stays in 16-lane group
        float p0 = expf(e0 - mx);
        float p1 = expf(e1 - mx);
        float num = p0 * h0[j] + p1 * h1[j];
        float den = p0 + p1;
#pragma unroll
        for (int off = 8; off > 0; off >>= 1) {
          num += __shfl_xor(num, off);
          den += __shfl_xor(den, off);
        }
        if (kk == 0) outb[(size_t)(oc0 + j) * NS] = num / den;
      }
    }
    // no trailing barrier needed: F reads only s_u/s_a/ceA; next query's
    // s_u writes (E') sit behind B1'+B2'; next C' touches only s_h1 whose
    // readers (this D) finished before B2.

    gv = gv_next;
#pragma unroll
    for (int c = 0; c < 6; ++c) pts[c] = pts_next[c];
  }
}

// ---------------------------------------------------------------------------
extern "C" void kernel_launch(void* const* d_in, const int* in_sizes, int n_in,
                              void* d_out, int out_size, void* d_ws,
                              size_t ws_size, hipStream_t stream) {
  (void)in_sizes; (void)n_in; (void)out_size; (void)ws_size;
  const float* xyz = (const float*)d_in[0];
  const float* points = (const float*)d_in[1];
  const float* w0 = (const float*)d_in[2];
  const float* b0 = (const float*)d_in[3];
  const float* g0 = (const float*)d_in[4];
  const float* be0 = (const float*)d_in[5];
  const float* m0 = (const float*)d_in[6];
  const float* v0 = (const float*)d_in[7];
  const float* w1 = (const float*)d_in[8];
  const float* b1 = (const float*)d_in[9];
  const float* g1 = (const float*)d_in[10];
  const float* be1 = (const float*)d_in[11];
  const float* m1 = (const float*)d_in[12];
  const float* v1 = (const float*)d_in[13];
  const float* w2 = (const float*)d_in[14];
  const float* b2 = (const float*)d_in[15];
  const float* g2 = (const float*)d_in[16];
  const float* be2 = (const float*)d_in[17];
  const float* m2 = (const float*)d_in[18];
  const float* v2 = (const float*)d_in[19];
  const float* a = (const float*)d_in[20];

  float* out0 = (float*)d_out;                  // [B,3,S]
  float* out1 = out0 + (size_t)NB * 3 * NS;     // [B,128,S]

  int* fps = (int*)d_ws;                                        // 32 KB
  float* nxyz = (float*)((char*)d_ws + 32768);                  // 96 KB
  float* ceA = (float*)((char*)d_ws + 131072);                  // 4 MB
  float4* gq = (float4*)((char*)d_ws + 131072 + 4194304);       // 4 MB

  hipFuncSetAttribute(reinterpret_cast<const void*>(mega_kernel),
                      hipFuncAttributeMaxDynamicSharedMemorySize, SMEM_BYTES);

  fps_kernel<<<NB, 512, 0, stream>>>(xyz, fps, nxyz, out0);
  ballq_kernel<<<NB * NS, 256, 0, stream>>>(xyz, nxyz, gq);
  center_kernel<<<NB * NS, 64, 0, stream>>>(points, nxyz, fps,
      w0, b0, g0, be0, m0, v0, w1, b1, g1, be1, m1, v1,
      w2, b2, g2, be2, m2, v2, a, ceA);
  mega_kernel<<<NB * NS / QPB, MEGA_THREADS, SMEM_BYTES, stream>>>(
      points, ceA, gq,
      w0, b0, g0, be0, m0, v0, w1, b1, g1, be1, m1, v1,
      w2, b2, g2, be2, m2, v2, a, out1);
}